// Round 1
// baseline (304.487 us; speedup 1.0000x reference)
//
#include <hip/hip_runtime.h>
#include <hip/hip_fp16.h>
#include <math.h>

typedef _Float16 f16;
typedef _Float16 f16x8 __attribute__((ext_vector_type(8)));
typedef float f32x4 __attribute__((ext_vector_type(4)));

#define BB 8
#define SS 2048
#define DD 256
#define HH 4
#define DHH 64

// ---------------------------------------------------------------------------
// Kernel 1: cast x -> fp16, pack W_qkv transposed [768][256] fp16, W_o^T fp16
// ---------------------------------------------------------------------------
__global__ __launch_bounds__(256) void prep_kernel(
    const float* __restrict__ x, const float* __restrict__ wq,
    const float* __restrict__ wk, const float* __restrict__ wv,
    const float* __restrict__ wo,
    f16* __restrict__ xh, f16* __restrict__ wqkvT, f16* __restrict__ woT) {
  int tid = blockIdx.x * blockDim.x + threadIdx.x;
  int stride = gridDim.x * blockDim.x;
  const int NX = BB * SS * DD;
  for (int i = tid; i < NX; i += stride) xh[i] = (f16)x[i];
  for (int i = tid; i < 768 * 256; i += stride) {
    int dout = i >> 8, k = i & 255;
    float v;
    if (dout < 256)      v = wq[k * 256 + dout];
    else if (dout < 512) v = wk[k * 256 + dout - 256];
    else                 v = wv[k * 256 + dout - 512];
    wqkvT[i] = (f16)v;
  }
  for (int i = tid; i < 256 * 256; i += stride) {
    int n = i >> 8, k = i & 255;
    woT[i] = (f16)wo[k * 256 + n];
  }
}

// ---------------------------------------------------------------------------
// Kernel 2: fused QKV projection GEMM.  C[16384,768] = xh[16384,256] @ W[256,768]
// Epilogue scatters to Q[b,h,s,64], K[b,h,s,64], V^T[b,h,64,s] (all fp16).
// 64x64 tile per workgroup, 4 waves x 16 rows, mfma_f32_16x16x32_f16.
// ---------------------------------------------------------------------------
__global__ __launch_bounds__(256) void qkv_gemm(
    const f16* __restrict__ xh, const f16* __restrict__ wT,
    f16* __restrict__ Q, f16* __restrict__ K, f16* __restrict__ VT) {
  int m0 = blockIdx.x * 64;
  int n0 = blockIdx.y * 64;
  int wave = threadIdx.x >> 6, lane = threadIdx.x & 63;
  int lm = lane & 15, quad = lane >> 4;
  const f16* arow = xh + (m0 + wave * 16 + lm) * 256 + quad * 8;
  f32x4 acc[4] = {};
  for (int kk = 0; kk < 256; kk += 32) {
    f16x8 a = *(const f16x8*)(arow + kk);
#pragma unroll
    for (int nt = 0; nt < 4; nt++) {
      f16x8 b = *(const f16x8*)(wT + (n0 + nt * 16 + lm) * 256 + kk + quad * 8);
      acc[nt] = __builtin_amdgcn_mfma_f32_16x16x32_f16(a, b, acc[nt], 0, 0, 0);
    }
  }
#pragma unroll
  for (int nt = 0; nt < 4; nt++) {
#pragma unroll
    for (int r = 0; r < 4; r++) {
      int t = m0 + wave * 16 + quad * 4 + r;
      int b = t >> 11, s = t & 2047;
      int dout = n0 + nt * 16 + lm;
      f16 v = (f16)acc[nt][r];
      if (dout < 256) {
        int h = dout >> 6, dh = dout & 63;
        Q[(((b * HH + h) * SS + s) << 6) + dh] = v;
      } else if (dout < 512) {
        int d2 = dout - 256; int h = d2 >> 6, dh = d2 & 63;
        K[(((b * HH + h) * SS + s) << 6) + dh] = v;
      } else {
        int d2 = dout - 512; int h = d2 >> 6, dh = d2 & 63;
        VT[((b * HH + h) * DHH + dh) * SS + s] = v;
      }
    }
  }
}

// ---------------------------------------------------------------------------
// Kernel 3: flash attention. One workgroup = (b, h, 128 q-rows); 4 waves each
// own 32 q-rows independently (no __syncthreads needed — per-wave LDS region).
// K-tile = 64 keys per iteration, online softmax, P transposed via padded LDS.
// ---------------------------------------------------------------------------
__global__ __launch_bounds__(256) void attn_kernel(
    const f16* __restrict__ Q, const f16* __restrict__ K,
    const f16* __restrict__ VT, f16* __restrict__ ctx) {
  // stride 72 halves = 144 B (16B multiple -> aligned b128 reads, benign 2-way banks)
  __shared__ __attribute__((aligned(16))) f16 lds_p[4][32][72];
  int qb = blockIdx.x, h = blockIdx.y, b = blockIdx.z;
  int wave = threadIdx.x >> 6, lane = threadIdx.x & 63;
  int lm = lane & 15, quad = lane >> 4;
  const f16* Qbh = Q + (size_t)(b * HH + h) * SS * DHH;
  const f16* Kbh = K + (size_t)(b * HH + h) * SS * DHH;
  const f16* Vbh = VT + (size_t)(b * HH + h) * DHH * SS;
  int q0 = qb * 128 + wave * 32;

  // Q fragments stay resident: A[m=lane&15][k=quad*8+j], 2 m-tiles x 2 k-steps
  f16x8 aq[2][2];
#pragma unroll
  for (int mt = 0; mt < 2; mt++)
#pragma unroll
    for (int kp = 0; kp < 2; kp++)
      aq[mt][kp] = *(const f16x8*)(Qbh + (q0 + mt * 16 + lm) * DHH + kp * 32 + quad * 8);

  f32x4 accO[2][4] = {};
  float mrow[2][4], lrow[2][4];
#pragma unroll
  for (int mt = 0; mt < 2; mt++)
#pragma unroll
    for (int r = 0; r < 4; r++) { mrow[mt][r] = -INFINITY; lrow[mt][r] = 0.f; }

  for (int key0 = 0; key0 < SS; key0 += 64) {
    // ---- S = Q K^T (scaled later) ----
    f32x4 accS[2][4] = {};
#pragma unroll
    for (int kp = 0; kp < 2; kp++) {
      f16x8 bk[4];
#pragma unroll
      for (int nt = 0; nt < 4; nt++)
        bk[nt] = *(const f16x8*)(Kbh + (key0 + nt * 16 + lm) * DHH + kp * 32 + quad * 8);
#pragma unroll
      for (int mt = 0; mt < 2; mt++)
#pragma unroll
        for (int nt = 0; nt < 4; nt++)
          accS[mt][nt] = __builtin_amdgcn_mfma_f32_16x16x32_f16(aq[mt][kp], bk[nt], accS[mt][nt], 0, 0, 0);
    }
    // ---- online softmax: row = quad*4+r lives in one 16-lane group ----
#pragma unroll
    for (int mt = 0; mt < 2; mt++) {
      float rmax[4], tsum[4], newm[4], alpha[4];
#pragma unroll
      for (int r = 0; r < 4; r++) {
        float v0 = fmaxf(fmaxf(accS[mt][0][r], accS[mt][1][r]),
                         fmaxf(accS[mt][2][r], accS[mt][3][r]));
        rmax[r] = v0 * 0.125f;
      }
#pragma unroll
      for (int r = 0; r < 4; r++) {
#pragma unroll
        for (int off = 8; off >= 1; off >>= 1)
          rmax[r] = fmaxf(rmax[r], __shfl_xor(rmax[r], off, 64));
        newm[r] = fmaxf(mrow[mt][r], rmax[r]);
        alpha[r] = __expf(mrow[mt][r] - newm[r]);  // -inf first tile -> 0
        mrow[mt][r] = newm[r];
        tsum[r] = 0.f;
      }
#pragma unroll
      for (int nt = 0; nt < 4; nt++) {
#pragma unroll
        for (int r = 0; r < 4; r++) {
          float p = __expf(accS[mt][nt][r] * 0.125f - newm[r]);
          tsum[r] += p;
          lds_p[wave][mt * 16 + quad * 4 + r][nt * 16 + lm] = (f16)p;
        }
      }
#pragma unroll
      for (int r = 0; r < 4; r++) {
#pragma unroll
        for (int off = 8; off >= 1; off >>= 1)
          tsum[r] += __shfl_xor(tsum[r], off, 64);
        lrow[mt][r] = lrow[mt][r] * alpha[r] + tsum[r];
      }
#pragma unroll
      for (int nt = 0; nt < 4; nt++)
#pragma unroll
        for (int r = 0; r < 4; r++)
          accO[mt][nt][r] *= alpha[r];
    }
    // ---- O += P V  (P re-read from LDS in A-layout; V^T gives contiguous B frags)
#pragma unroll
    for (int kp = 0; kp < 2; kp++) {
      f16x8 bv[4];
#pragma unroll
      for (int nt = 0; nt < 4; nt++)
        bv[nt] = *(const f16x8*)(Vbh + (nt * 16 + lm) * SS + key0 + kp * 32 + quad * 8);
      f16x8 ap[2];
#pragma unroll
      for (int mt = 0; mt < 2; mt++)
        ap[mt] = *(const f16x8*)(&lds_p[wave][mt * 16 + lm][kp * 32 + quad * 8]);
#pragma unroll
      for (int mt = 0; mt < 2; mt++)
#pragma unroll
        for (int nt = 0; nt < 4; nt++)
          accO[mt][nt] = __builtin_amdgcn_mfma_f32_16x16x32_f16(ap[mt], bv[nt], accO[mt][nt], 0, 0, 0);
    }
  }
  // ---- epilogue: ctx[b,s, h*64+dh] fp16 ----
#pragma unroll
  for (int mt = 0; mt < 2; mt++) {
    float rinv[4];
#pragma unroll
    for (int r = 0; r < 4; r++) rinv[r] = 1.0f / lrow[mt][r];
#pragma unroll
    for (int nt = 0; nt < 4; nt++)
#pragma unroll
      for (int r = 0; r < 4; r++) {
        int s = q0 + mt * 16 + quad * 4 + r;
        ctx[(size_t)(b * SS + s) * DD + h * DHH + nt * 16 + lm] =
            (f16)(accO[mt][nt][r] * rinv[r]);
      }
  }
}

// ---------------------------------------------------------------------------
// Kernel 4: out = ctx @ W_o + b_o   (fp32 output)
// ---------------------------------------------------------------------------
__global__ __launch_bounds__(256) void out_gemm(
    const f16* __restrict__ ctxh, const f16* __restrict__ woT,
    const float* __restrict__ bo, float* __restrict__ out) {
  int m0 = blockIdx.x * 64;
  int n0 = blockIdx.y * 64;
  int wave = threadIdx.x >> 6, lane = threadIdx.x & 63;
  int lm = lane & 15, quad = lane >> 4;
  const f16* arow = ctxh + (m0 + wave * 16 + lm) * 256 + quad * 8;
  f32x4 acc[4] = {};
  for (int kk = 0; kk < 256; kk += 32) {
    f16x8 a = *(const f16x8*)(arow + kk);
#pragma unroll
    for (int nt = 0; nt < 4; nt++) {
      f16x8 bfr = *(const f16x8*)(woT + (n0 + nt * 16 + lm) * 256 + kk + quad * 8);
      acc[nt] = __builtin_amdgcn_mfma_f32_16x16x32_f16(a, bfr, acc[nt], 0, 0, 0);
    }
  }
#pragma unroll
  for (int nt = 0; nt < 4; nt++) {
    int dout = n0 + nt * 16 + lm;
    float bias = bo[dout];
#pragma unroll
    for (int r = 0; r < 4; r++) {
      int t = m0 + wave * 16 + quad * 4 + r;
      out[(size_t)t * 256 + dout] = acc[nt][r] + bias;
    }
  }
}

// ---------------------------------------------------------------------------
extern "C" void kernel_launch(void* const* d_in, const int* in_sizes, int n_in,
                              void* d_out, int out_size, void* d_ws, size_t ws_size,
                              hipStream_t stream) {
  const float* x  = (const float*)d_in[0];
  const float* wq = (const float*)d_in[1];
  const float* wk = (const float*)d_in[2];
  const float* wv = (const float*)d_in[3];
  const float* wo = (const float*)d_in[4];
  const float* bo = (const float*)d_in[5];
  float* out = (float*)d_out;

  char* ws = (char*)d_ws;
  const size_t SZ = 8388608;  // 16384*256*2 bytes (one fp16 [16384,256] buffer)
  f16* xh    = (f16*)(ws);
  f16* Qb    = (f16*)(ws + SZ);
  f16* Kb    = (f16*)(ws + 2 * SZ);
  f16* VTb   = (f16*)(ws + 3 * SZ);
  f16* ctxh  = (f16*)(ws + 4 * SZ);
  f16* wqkvT = (f16*)(ws + 5 * SZ);            // 768*256*2 = 393216
  f16* woT   = (f16*)(ws + 5 * SZ + 393216);   // 256*256*2 = 131072

  hipLaunchKernelGGL(prep_kernel, dim3(1024), dim3(256), 0, stream,
                     x, wq, wk, wv, wo, xh, wqkvT, woT);
  hipLaunchKernelGGL(qkv_gemm, dim3(256, 12), dim3(256), 0, stream,
                     xh, wqkvT, Qb, Kb, VTb);
  hipLaunchKernelGGL(attn_kernel, dim3(16, 4, 8), dim3(256), 0, stream,
                     Qb, Kb, VTb, ctxh);
  hipLaunchKernelGGL(out_gemm, dim3(256, 4), dim3(256), 0, stream,
                     ctxh, woT, bo, out);
}